// Round 3
// baseline (261.693 us; speedup 1.0000x reference)
//
#include <hip/hip_runtime.h>
#include <hip/hip_fp16.h>
#include <stdint.h>

typedef _Float16 f16;
typedef _Float16 half8  __attribute__((ext_vector_type(8)));
typedef _Float16 half4v __attribute__((ext_vector_type(4)));
typedef float    f32x4  __attribute__((ext_vector_type(4)));

#define NBATCH 4
#define SEQ    4096
#define DMODEL 256
#define DHEAD  64
#define NQKV   192

// ---------------------------------------------------------------------------
// Kernel A: qkv = x @ W_qkv + b_qkv (fp32 VALU). Emits:
//   qh[row][d]  fp16, pre-scaled by 1/8 (exact pow2)
//   kh[row][d]  fp16 row-major
//   vt[b][d][seq] fp16 TRANSPOSED (so attn's PV B-frag reads are contiguous)
// ---------------------------------------------------------------------------
__global__ __launch_bounds__(256) void qkv_proj(
    const float* __restrict__ x, const float* __restrict__ Wq,
    const float* __restrict__ bq,
    f16* __restrict__ qh, f16* __restrict__ kh, f16* __restrict__ vt)
{
  __shared__ float xs[32][64];      // 8 KB
  __shared__ float wsh[64][NQKV];   // 48 KB
  const int t = threadIdx.x;
  const int row0 = blockIdx.x * 32;
  const int cg = t & 31;            // 32 col-groups x 6 cols
  const int rg = t >> 5;            // 8 row-groups x 4 rows
  const int n0 = cg * 6;
  const int m0 = rg * 4;
  float acc[4][6];
#pragma unroll
  for (int i = 0; i < 4; ++i)
#pragma unroll
    for (int j = 0; j < 6; ++j) acc[i][j] = 0.f;

  for (int kc = 0; kc < 4; ++kc) {
    const int k0 = kc * 64;
#pragma unroll
    for (int j = 0; j < 8; ++j) {
      int li = j * 256 + t;
      xs[li >> 6][li & 63] = x[(size_t)(row0 + (li >> 6)) * DMODEL + k0 + (li & 63)];
    }
#pragma unroll
    for (int j = 0; j < 48; ++j) {
      int li = j * 256 + t;
      int r = li / NQKV, c = li % NQKV;
      wsh[r][c] = Wq[(size_t)(k0 + r) * NQKV + c];
    }
    __syncthreads();
#pragma unroll
    for (int kk4 = 0; kk4 < 16; ++kk4) {
      float4 a4[4];
#pragma unroll
      for (int i = 0; i < 4; ++i) a4[i] = *(const float4*)&xs[m0 + i][kk4 * 4];
#pragma unroll
      for (int e = 0; e < 4; ++e) {
        const int kk = kk4 * 4 + e;
        float2 b01 = *(const float2*)&wsh[kk][n0];
        float2 b23 = *(const float2*)&wsh[kk][n0 + 2];
        float2 b45 = *(const float2*)&wsh[kk][n0 + 4];
#pragma unroll
        for (int i = 0; i < 4; ++i) {
          const float a = (e == 0) ? a4[i].x : (e == 1) ? a4[i].y : (e == 2) ? a4[i].z : a4[i].w;
          acc[i][0] = fmaf(a, b01.x, acc[i][0]);
          acc[i][1] = fmaf(a, b01.y, acc[i][1]);
          acc[i][2] = fmaf(a, b23.x, acc[i][2]);
          acc[i][3] = fmaf(a, b23.y, acc[i][3]);
          acc[i][4] = fmaf(a, b45.x, acc[i][4]);
          acc[i][5] = fmaf(a, b45.y, acc[i][5]);
        }
      }
    }
    __syncthreads();
  }
  const int bi  = row0 >> 12;           // batch (rows 0..4095 per batch, row0%32==0)
  const int seq0 = (row0 & (SEQ - 1)) + m0;
#pragma unroll
  for (int j = 0; j < 6; ++j) {
    const int n = n0 + j;
    const float b = bq[n];
    const float v0 = acc[0][j] + b, v1 = acc[1][j] + b;
    const float v2 = acc[2][j] + b, v3 = acc[3][j] + b;
    if (n < 64) {
      const size_t r = (size_t)row0 + m0;
      qh[(r + 0) * DHEAD + n] = (f16)(v0 * 0.125f);
      qh[(r + 1) * DHEAD + n] = (f16)(v1 * 0.125f);
      qh[(r + 2) * DHEAD + n] = (f16)(v2 * 0.125f);
      qh[(r + 3) * DHEAD + n] = (f16)(v3 * 0.125f);
    } else if (n < 128) {
      const size_t r = (size_t)row0 + m0;
      kh[(r + 0) * DHEAD + (n - 64)] = (f16)v0;
      kh[(r + 1) * DHEAD + (n - 64)] = (f16)v1;
      kh[(r + 2) * DHEAD + (n - 64)] = (f16)v2;
      kh[(r + 3) * DHEAD + (n - 64)] = (f16)v3;
    } else {
      // transposed V: 4 consecutive seq positions, same d -> one 8B store
      half4v pk = {(f16)v0, (f16)v1, (f16)v2, (f16)v3};
      *(half4v*)(vt + (size_t)bi * DHEAD * SEQ + (size_t)(n - 128) * SEQ + seq0) = pk;
    }
  }
}

// ---------------------------------------------------------------------------
// Kernel B: fused scores -> top-k threshold -> masked softmax -> PV.
// WG = 512 threads (8 waves) per 16 q-rows; wave w owns keys [512w, 512w+512).
// No LDS in main loops: K rows feed A-frags directly (16B global loads), V^T
// rows feed PV B-frags directly (8B global loads). Distance-1 reg prefetch.
// ---------------------------------------------------------------------------
#define WAVES  8
#define CHUNK  32
#define NCHUNK 16

__device__ __forceinline__ void load_k_chunk(const f16* __restrict__ base, uint4* kb) {
  kb[0] = *(const uint4*)(base);                     // kt=0, halves [8g..8g+8)
  kb[1] = *(const uint4*)(base + 32);                // kt=0, halves [32+8g..)
  kb[2] = *(const uint4*)(base + 16 * DHEAD);        // kt=1
  kb[3] = *(const uint4*)(base + 16 * DHEAD + 32);
}

__device__ __forceinline__ void load_v_chunk(const f16* __restrict__ base, half4v* vb) {
#pragma unroll
  for (int pnl = 0; pnl < 4; ++pnl) {
    vb[pnl * 2 + 0] = *(const half4v*)(base + (size_t)pnl * 16 * SEQ);        // kt=0
    vb[pnl * 2 + 1] = *(const half4v*)(base + (size_t)pnl * 16 * SEQ + 16);   // kt=1
  }
}

__global__ __launch_bounds__(512) void attn_fused(
    const f16* __restrict__ qh, const f16* __restrict__ kh,
    const f16* __restrict__ vt, float* __restrict__ attn_out)
{
  __shared__ float red[WAVES][16 * DHEAD];   // 32 KB, epilogue reduce only
  __shared__ float selbuf[2][WAVES][16];
  __shared__ float zrow[16];

  const int tid = threadIdx.x;
  const int w = tid >> 6;
  const int l = tid & 63;
  const int qr = l & 15;          // q-row (QK^T) / d-col (PV) within tile
  const int g  = l >> 4;          // lane group 0..3
  const int bi = blockIdx.x >> 8;
  const int rb = blockIdx.x & 255;
  const size_t qrow0  = (size_t)bi * SEQ + (size_t)rb * 16;
  const size_t kvbase = (size_t)bi * SEQ * DHEAD;
  const int key0 = w * (CHUNK * NCHUNK);

  // Q fragments (B operand), q pre-scaled by 1/8 in qh.
  half8 qf0, qf1;
  {
    const f16* qp = qh + (qrow0 + qr) * DHEAD;
    qf0 = *(const half8*)(qp + 8 * g);
    qf1 = *(const half8*)(qp + 32 + 8 * g);
  }

  half4v P[2 * NCHUNK];           // 128 fp16 scores/lane
  float mn = 1e30f, mx = -1e30f;

  // ---- QK^T: direct global A-frag loads, distance-1 prefetch ----
  const f16* kbase = kh + kvbase + (size_t)(key0 + qr) * DHEAD + g * 8;
  uint4 kb[2][4];
  load_k_chunk(kbase, kb[0]);
#pragma unroll
  for (int kc = 0; kc < NCHUNK; ++kc) {
    const int cur = kc & 1;
    if (kc + 1 < NCHUNK) load_k_chunk(kbase + (size_t)(kc + 1) * CHUNK * DHEAD, kb[cur ^ 1]);
#pragma unroll
    for (int kt = 0; kt < 2; ++kt) {
      f32x4 c = {0.f, 0.f, 0.f, 0.f};
      half8 kf0 = *(const half8*)&kb[cur][kt * 2 + 0];
      half8 kf1 = *(const half8*)&kb[cur][kt * 2 + 1];
      c = __builtin_amdgcn_mfma_f32_16x16x32_f16(kf0, qf0, c, 0, 0, 0);
      c = __builtin_amdgcn_mfma_f32_16x16x32_f16(kf1, qf1, c, 0, 0, 0);
      mn = fminf(mn, fminf(fminf(c[0], c[1]), fminf(c[2], c[3])));
      mx = fmaxf(mx, fmaxf(fmaxf(c[0], c[1]), fmaxf(c[2], c[3])));
      P[kc * 2 + kt] = (half4v){(f16)c[0], (f16)c[1], (f16)c[2], (f16)c[3]};
    }
  }

  // ---- per-row min/max across lanes and waves ----
  mn = fminf(mn, __shfl_xor(mn, 16, 64));
  mn = fminf(mn, __shfl_xor(mn, 32, 64));
  mx = fmaxf(mx, __shfl_xor(mx, 16, 64));
  mx = fmaxf(mx, __shfl_xor(mx, 32, 64));
  if (l < 16) { selbuf[0][w][l] = mn; selbuf[1][w][l] = mx; }
  __syncthreads();
  float lo = 1e30f, hi = -1e30f;
#pragma unroll
  for (int j = 0; j < WAVES; ++j) {
    lo = fminf(lo, selbuf[0][j][qr]);
    hi = fmaxf(hi, selbuf[1][j][qr]);
  }
  __syncthreads();   // all lo/hi reads done before iter 0 overwrites selbuf[0]

  // ---- bisection on sampled count (1024 of 4096; target 512); 1 barrier/iter
  // (alternating buffers make the pre-write barrier redundant) ----
#pragma unroll
  for (int it = 0; it < 10; ++it) {
    const float tm = 0.5f * (lo + hi);
    const f16 th = (f16)tm;
    int cnt = 0;
#pragma unroll
    for (int j = 0; j < 2 * NCHUNK; j += 4) {
      half4v s = P[j];
      cnt += (s[0] >= th) + (s[1] >= th) + (s[2] >= th) + (s[3] >= th);
    }
    cnt += __shfl_xor(cnt, 16, 64);
    cnt += __shfl_xor(cnt, 32, 64);
    if (l < 16) selbuf[it & 1][w][l] = (float)cnt;
    __syncthreads();
    float tot = 0.f;
#pragma unroll
    for (int j = 0; j < WAVES; ++j) tot += selbuf[it & 1][j][qr];
    if (tot >= 512.f) lo = tm; else hi = tm;
  }
  const float thr = lo;

  // ---- exp in place (masked -> exp(0)=1, matches softmax(scores*mask)) ----
  float z = 0.f;
#pragma unroll
  for (int j = 0; j < 2 * NCHUNK; ++j) {
    half4v s = P[j];
    float p0 = (float)s[0], p1 = (float)s[1], p2 = (float)s[2], p3 = (float)s[3];
    p0 = (p0 >= thr) ? __expf(p0) : 1.f;
    p1 = (p1 >= thr) ? __expf(p1) : 1.f;
    p2 = (p2 >= thr) ? __expf(p2) : 1.f;
    p3 = (p3 >= thr) ? __expf(p3) : 1.f;
    z += (p0 + p1) + (p2 + p3);
    P[j] = (half4v){(f16)p0, (f16)p1, (f16)p2, (f16)p3};
  }
  z += __shfl_xor(z, 16, 64);
  z += __shfl_xor(z, 32, 64);
  // last bisection reads were of selbuf[1]; selbuf[0] is free to overwrite
  if (l < 16) selbuf[0][w][l] = z;
  __syncthreads();
  if (w == 0 && l < 16) {
    float t2 = 0.f;
#pragma unroll
    for (int j = 0; j < WAVES; ++j) t2 += selbuf[0][j][l];
    zrow[l] = t2;   // consumed after the post-PV barrier
  }

  // ---- PV: A-frag = P (QK^T D-layout == A-frag layout), B-frag from vT ----
  f32x4 acc[4];
#pragma unroll
  for (int p = 0; p < 4; ++p) acc[p] = (f32x4){0.f, 0.f, 0.f, 0.f};

  const f16* vbase = vt + (size_t)bi * DHEAD * SEQ + (size_t)qr * SEQ + key0 + 4 * g;
  half4v vb[2][8];
  load_v_chunk(vbase, vb[0]);
#pragma unroll
  for (int kc = 0; kc < NCHUNK; ++kc) {
    const int cur = kc & 1;
    if (kc + 1 < NCHUNK) load_v_chunk(vbase + (kc + 1) * CHUNK, vb[cur ^ 1]);
#pragma unroll
    for (int kt = 0; kt < 2; ++kt) {
      const half4v pa = P[kc * 2 + kt];
#pragma unroll
      for (int pnl = 0; pnl < 4; ++pnl) {
        acc[pnl] = __builtin_amdgcn_mfma_f32_16x16x16f16(pa, vb[cur][pnl * 2 + kt], acc[pnl], 0, 0, 0);
      }
    }
  }

  // ---- cross-wave reduce + divide by Z ----
#pragma unroll
  for (int pnl = 0; pnl < 4; ++pnl)
#pragma unroll
    for (int r = 0; r < 4; ++r)
      red[w][(4 * g + r) * DHEAD + pnl * 16 + qr] = acc[pnl][r];
  __syncthreads();
#pragma unroll
  for (int oo = 0; oo < 2; ++oo) {
    const int o = tid * 2 + oo;
    const int i = o >> 6, n = o & 63;
    float s = 0.f;
#pragma unroll
    for (int j = 0; j < WAVES; ++j) s += red[j][i * DHEAD + n];
    attn_out[(qrow0 + i) * DHEAD + n] = s / zrow[i];
  }
}

// ---------------------------------------------------------------------------
// Kernel C: out = attn_out @ W_out + b_out (fp32). 32 rows x 256 cols per WG.
// ---------------------------------------------------------------------------
__global__ __launch_bounds__(256) void out_proj(
    const float* __restrict__ attn, const float* __restrict__ Wo,
    const float* __restrict__ bo, float* __restrict__ out)
{
  __shared__ float wl[32][DMODEL];  // 32 KB
  __shared__ float at[32][DHEAD];   // 8 KB
  const int t = threadIdx.x;
  const int row0 = blockIdx.x * 32;
  const int rg = t >> 6;
  const int cg = t & 63;
  float acc[8][4];
#pragma unroll
  for (int i = 0; i < 8; ++i) { acc[i][0] = acc[i][1] = acc[i][2] = acc[i][3] = 0.f; }
#pragma unroll
  for (int j = 0; j < 8; ++j) {
    int li = j * 256 + t;
    at[li >> 6][li & 63] = attn[(size_t)(row0 + (li >> 6)) * DHEAD + (li & 63)];
  }
  for (int kc = 0; kc < 2; ++kc) {
#pragma unroll
    for (int j = 0; j < 32; ++j) {
      int li = j * 256 + t;
      wl[li >> 8][li & 255] = Wo[(size_t)(kc * 32 + (li >> 8)) * DMODEL + (li & 255)];
    }
    __syncthreads();
#pragma unroll
    for (int kk = 0; kk < 32; ++kk) {
      const float4 wv = *(const float4*)&wl[kk][cg * 4];
#pragma unroll
      for (int i = 0; i < 8; ++i) {
        const float a = at[rg * 8 + i][kc * 32 + kk];
        acc[i][0] = fmaf(a, wv.x, acc[i][0]);
        acc[i][1] = fmaf(a, wv.y, acc[i][1]);
        acc[i][2] = fmaf(a, wv.z, acc[i][2]);
        acc[i][3] = fmaf(a, wv.w, acc[i][3]);
      }
    }
    __syncthreads();
  }
  const float4 bb = *(const float4*)&bo[cg * 4];
#pragma unroll
  for (int i = 0; i < 8; ++i) {
    float4 r;
    r.x = acc[i][0] + bb.x; r.y = acc[i][1] + bb.y;
    r.z = acc[i][2] + bb.z; r.w = acc[i][3] + bb.w;
    *(float4*)&out[(size_t)(row0 + rg * 8 + i) * DMODEL + cg * 4] = r;
  }
}

// ---------------------------------------------------------------------------
extern "C" void kernel_launch(void* const* d_in, const int* in_sizes, int n_in,
                              void* d_out, int out_size, void* d_ws, size_t ws_size,
                              hipStream_t stream)
{
  (void)in_sizes; (void)n_in; (void)out_size; (void)ws_size;
  const float* x  = (const float*)d_in[0];
  const float* Wq = (const float*)d_in[1];
  const float* bq = (const float*)d_in[2];
  const float* Wo = (const float*)d_in[3];
  const float* bo = (const float*)d_in[4];
  float* out = (float*)d_out;
  char* ws = (char*)d_ws;
  f16* qh = (f16*)(ws);                              // 2 MB
  f16* kh = (f16*)(ws + (size_t)(2 << 20));          // 2 MB
  f16* vt = (f16*)(ws + (size_t)(4 << 20));          // 2 MB (transposed V)
  float* attn = (float*)(ws + (size_t)(6 << 20));    // 4 MB

  hipLaunchKernelGGL(qkv_proj,   dim3(512),  dim3(256), 0, stream, x, Wq, bq, qh, kh, vt);
  hipLaunchKernelGGL(attn_fused, dim3(1024), dim3(512), 0, stream, qh, kh, vt, attn);
  hipLaunchKernelGGL(out_proj,   dim3(512),  dim3(256), 0, stream, attn, Wo, bo, out);
}

// Round 4
// 184.126 us; speedup vs baseline: 1.4213x; 1.4213x over previous
//
#include <hip/hip_runtime.h>
#include <hip/hip_fp16.h>
#include <stdint.h>

typedef _Float16 f16;
typedef _Float16 half8  __attribute__((ext_vector_type(8)));
typedef _Float16 half4v __attribute__((ext_vector_type(4)));
typedef float    f32x4  __attribute__((ext_vector_type(4)));

#define NBATCH 4
#define SEQ    4096
#define DMODEL 256
#define DHEAD  64
#define NQKV   192

// ---------------------------------------------------------------------------
// Kernel A: qkv = x @ W_qkv + b_qkv (fp32 VALU). Emits:
//   qh[row][d]   fp16, pre-scaled by 1/8 (exact pow2)
//   kh[row][d]   fp16 row-major
//   vt[b][d][seq] fp16 TRANSPOSED (PV stages this d-major into LDS)
// ---------------------------------------------------------------------------
__global__ __launch_bounds__(256) void qkv_proj(
    const float* __restrict__ x, const float* __restrict__ Wq,
    const float* __restrict__ bq,
    f16* __restrict__ qh, f16* __restrict__ kh, f16* __restrict__ vt)
{
  __shared__ float xs[32][64];      // 8 KB
  __shared__ float wsh[64][NQKV];   // 48 KB
  const int t = threadIdx.x;
  const int row0 = blockIdx.x * 32;
  const int cg = t & 31;            // 32 col-groups x 6 cols
  const int rg = t >> 5;            // 8 row-groups x 4 rows
  const int n0 = cg * 6;
  const int m0 = rg * 4;
  float acc[4][6];
#pragma unroll
  for (int i = 0; i < 4; ++i)
#pragma unroll
    for (int j = 0; j < 6; ++j) acc[i][j] = 0.f;

  for (int kc = 0; kc < 4; ++kc) {
    const int k0 = kc * 64;
#pragma unroll
    for (int j = 0; j < 8; ++j) {
      int li = j * 256 + t;
      xs[li >> 6][li & 63] = x[(size_t)(row0 + (li >> 6)) * DMODEL + k0 + (li & 63)];
    }
#pragma unroll
    for (int j = 0; j < 48; ++j) {
      int li = j * 256 + t;
      int r = li / NQKV, c = li % NQKV;
      wsh[r][c] = Wq[(size_t)(k0 + r) * NQKV + c];
    }
    __syncthreads();
#pragma unroll
    for (int kk4 = 0; kk4 < 16; ++kk4) {
      float4 a4[4];
#pragma unroll
      for (int i = 0; i < 4; ++i) a4[i] = *(const float4*)&xs[m0 + i][kk4 * 4];
#pragma unroll
      for (int e = 0; e < 4; ++e) {
        const int kk = kk4 * 4 + e;
        float2 b01 = *(const float2*)&wsh[kk][n0];
        float2 b23 = *(const float2*)&wsh[kk][n0 + 2];
        float2 b45 = *(const float2*)&wsh[kk][n0 + 4];
#pragma unroll
        for (int i = 0; i < 4; ++i) {
          const float a = (e == 0) ? a4[i].x : (e == 1) ? a4[i].y : (e == 2) ? a4[i].z : a4[i].w;
          acc[i][0] = fmaf(a, b01.x, acc[i][0]);
          acc[i][1] = fmaf(a, b01.y, acc[i][1]);
          acc[i][2] = fmaf(a, b23.x, acc[i][2]);
          acc[i][3] = fmaf(a, b23.y, acc[i][3]);
          acc[i][4] = fmaf(a, b45.x, acc[i][4]);
          acc[i][5] = fmaf(a, b45.y, acc[i][5]);
        }
      }
    }
    __syncthreads();
  }
  const int bi  = row0 >> 12;           // batch
  const int seq0 = (row0 & (SEQ - 1)) + m0;
#pragma unroll
  for (int j = 0; j < 6; ++j) {
    const int n = n0 + j;
    const float b = bq[n];
    const float v0 = acc[0][j] + b, v1 = acc[1][j] + b;
    const float v2 = acc[2][j] + b, v3 = acc[3][j] + b;
    if (n < 64) {
      const size_t r = (size_t)row0 + m0;
      qh[(r + 0) * DHEAD + n] = (f16)(v0 * 0.125f);
      qh[(r + 1) * DHEAD + n] = (f16)(v1 * 0.125f);
      qh[(r + 2) * DHEAD + n] = (f16)(v2 * 0.125f);
      qh[(r + 3) * DHEAD + n] = (f16)(v3 * 0.125f);
    } else if (n < 128) {
      const size_t r = (size_t)row0 + m0;
      kh[(r + 0) * DHEAD + (n - 64)] = (f16)v0;
      kh[(r + 1) * DHEAD + (n - 64)] = (f16)v1;
      kh[(r + 2) * DHEAD + (n - 64)] = (f16)v2;
      kh[(r + 3) * DHEAD + (n - 64)] = (f16)v3;
    } else {
      // transposed V: 4 consecutive seq positions, same d -> one 8B store
      half4v pk = {(f16)v0, (f16)v1, (f16)v2, (f16)v3};
      *(half4v*)(vt + (size_t)bi * DHEAD * SEQ + (size_t)(n - 128) * SEQ + seq0) = pk;
    }
  }
}

// ---------------------------------------------------------------------------
// Kernel B: fused scores -> top-k threshold -> masked softmax -> PV.
// Round-2 LDS-staged structure. PV change: V staged d-major [64][40] from vt
// so each B-frag is one contiguous ds_read_b64 (was 32x ds_read_u16/chunk).
// ---------------------------------------------------------------------------
#define WAVES  8
#define CHUNK  32
#define NCHUNK 16
#define VPAD   40      // V LDS row stride in halves (80 B, 16B-aligned, bank-spread)
#define WSTG   2560    // per-wave staging halves (5120 B >= max(K 4KB, V 5KB, red 4KB))

__global__ __launch_bounds__(512) void attn_fused(
    const f16* __restrict__ qh, const f16* __restrict__ kh,
    const f16* __restrict__ vt, float* __restrict__ attn_out)
{
  __shared__ f16 stage[WAVES][WSTG];          // 40 KB, wave-private
  __shared__ float selbuf[2][WAVES][16];
  __shared__ float zrow[16];

  const int tid = threadIdx.x;
  const int w = tid >> 6;
  const int l = tid & 63;
  const int qr = l & 15;          // q-row (QK^T) / d-col (PV) within tile
  const int g  = l >> 4;          // lane group 0..3
  const int bi = blockIdx.x >> 8;
  const int rb = blockIdx.x & 255;
  const size_t qrow0  = (size_t)bi * SEQ + (size_t)rb * 16;
  const size_t kvbase = (size_t)bi * SEQ * DHEAD;
  const int key0 = w * (CHUNK * NCHUNK);

  f16* const myst = &stage[w][0];

  // Q fragments (B operand), q pre-scaled by 1/8 in qh.
  half8 qf0, qf1;
  {
    const f16* qp = qh + (qrow0 + qr) * DHEAD;
    qf0 = *(const half8*)(qp + 8 * g);
    qf1 = *(const half8*)(qp + 32 + 8 * g);
  }

  half4v P[2 * NCHUNK];           // 128 fp16 scores/lane
  float mn = 1e30f, mx = -1e30f;

  // ---- QK^T: stage K chunk (swizzled), 2 MFMAs per 16-key tile ----
#pragma unroll
  for (int kc = 0; kc < NCHUNK; ++kc) {
    const f16* src = kh + kvbase + (size_t)(key0 + kc * CHUNK) * DHEAD;
#pragma unroll
    for (int i = 0; i < 4; ++i) {
      const int keyl = i * 8 + (l >> 3);
      const int c8 = l & 7;
      uint4 d = *(const uint4*)(src + keyl * DHEAD + c8 * 8);
      *(uint4*)(myst + keyl * DHEAD + ((c8 ^ (keyl & 7)) * 8)) = d;
    }
    // wave-private region: DS ops are in-order per wave; no barrier needed.
#pragma unroll
    for (int kt = 0; kt < 2; ++kt) {
      f32x4 c = {0.f, 0.f, 0.f, 0.f};
      const int keyl = kt * 16 + qr;   // A-row = key
      {
        const int ch0 = g;
        half8 kf0 = *(const half8*)(myst + keyl * DHEAD + ((ch0 ^ (keyl & 7)) * 8));
        c = __builtin_amdgcn_mfma_f32_16x16x32_f16(kf0, qf0, c, 0, 0, 0);
        const int ch1 = 4 + g;
        half8 kf1 = *(const half8*)(myst + keyl * DHEAD + ((ch1 ^ (keyl & 7)) * 8));
        c = __builtin_amdgcn_mfma_f32_16x16x32_f16(kf1, qf1, c, 0, 0, 0);
      }
      mn = fminf(mn, fminf(fminf(c[0], c[1]), fminf(c[2], c[3])));
      mx = fmaxf(mx, fmaxf(fmaxf(c[0], c[1]), fmaxf(c[2], c[3])));
      P[kc * 2 + kt] = (half4v){(f16)c[0], (f16)c[1], (f16)c[2], (f16)c[3]};
    }
  }

  // ---- per-row min/max across lanes and waves ----
  mn = fminf(mn, __shfl_xor(mn, 16, 64));
  mn = fminf(mn, __shfl_xor(mn, 32, 64));
  mx = fmaxf(mx, __shfl_xor(mx, 16, 64));
  mx = fmaxf(mx, __shfl_xor(mx, 32, 64));
  __syncthreads();
  if (l < 16) { selbuf[0][w][l] = mn; selbuf[1][w][l] = mx; }
  __syncthreads();
  float lo = 1e30f, hi = -1e30f;
#pragma unroll
  for (int j = 0; j < WAVES; ++j) {
    lo = fminf(lo, selbuf[0][j][qr]);
    hi = fmaxf(hi, selbuf[1][j][qr]);
  }
  __syncthreads();   // lo/hi reads complete before iter 0 overwrites selbuf[0]

  // ---- bisection on sampled count (1024 of 4096; target 512) ----
#pragma unroll
  for (int it = 0; it < 10; ++it) {
    const float tm = 0.5f * (lo + hi);
    const f16 th = (f16)tm;
    int cnt = 0;
#pragma unroll
    for (int j = 0; j < 2 * NCHUNK; j += 4) {
      half4v s = P[j];
      cnt += (s[0] >= th) + (s[1] >= th) + (s[2] >= th) + (s[3] >= th);
    }
    cnt += __shfl_xor(cnt, 16, 64);
    cnt += __shfl_xor(cnt, 32, 64);
    if (l < 16) selbuf[it & 1][w][l] = (float)cnt;
    __syncthreads();
    float tot = 0.f;
#pragma unroll
    for (int j = 0; j < WAVES; ++j) tot += selbuf[it & 1][j][qr];
    if (tot >= 512.f) lo = tm; else hi = tm;
  }
  const float thr = lo;

  // ---- exp in place (masked -> exp(0)=1, matches softmax(scores*mask)) ----
  float z = 0.f;
#pragma unroll
  for (int j = 0; j < 2 * NCHUNK; ++j) {
    half4v s = P[j];
    float p0 = (float)s[0], p1 = (float)s[1], p2 = (float)s[2], p3 = (float)s[3];
    p0 = (p0 >= thr) ? __expf(p0) : 1.f;
    p1 = (p1 >= thr) ? __expf(p1) : 1.f;
    p2 = (p2 >= thr) ? __expf(p2) : 1.f;
    p3 = (p3 >= thr) ? __expf(p3) : 1.f;
    z += (p0 + p1) + (p2 + p3);
    P[j] = (half4v){(f16)p0, (f16)p1, (f16)p2, (f16)p3};
  }
  z += __shfl_xor(z, 16, 64);
  z += __shfl_xor(z, 32, 64);
  // last bisection reads were selbuf[1]; selbuf[0] free to overwrite
  if (l < 16) selbuf[0][w][l] = z;
  __syncthreads();
  if (w == 0 && l < 16) {
    float t2 = 0.f;
#pragma unroll
    for (int j = 0; j < WAVES; ++j) t2 += selbuf[0][j][l];
    zrow[l] = t2;   // consumed after the post-PV barrier
  }

  // ---- PV: A-frag = P; V staged d-major [64][VPAD] -> B-frag = 1 b64 read ----
  f32x4 acc[4];
#pragma unroll
  for (int p = 0; p < 4; ++p) acc[p] = (f32x4){0.f, 0.f, 0.f, 0.f};

  const f16* vsrc0 = vt + (size_t)bi * DHEAD * SEQ + key0;
#pragma unroll
  for (int kc = 0; kc < NCHUNK; ++kc) {
    const f16* src = vsrc0 + kc * CHUNK;
#pragma unroll
    for (int i = 0; i < 4; ++i) {
      const int d = i * 16 + (l >> 2);        // 16 d-rows per instr
      const int ko = (l & 3) * 8;             // 8 keys (16B) per lane
      uint4 dta = *(const uint4*)(src + (size_t)d * SEQ + ko);
      *(uint4*)(myst + d * VPAD + ko) = dta;  // b128 write, 16B-aligned (VPAD*2=80)
    }
#pragma unroll
    for (int kt = 0; kt < 2; ++kt) {
      const half4v pa = P[kc * 2 + kt];
#pragma unroll
      for (int pnl = 0; pnl < 4; ++pnl) {
        // B[k=16kt+4g+e][n=16pnl+qr] = vls[d=16pnl+qr][16kt+4g+e]: contiguous
        half4v vv = *(const half4v*)(myst + (16 * pnl + qr) * VPAD + 16 * kt + 4 * g);
        acc[pnl] = __builtin_amdgcn_mfma_f32_16x16x16f16(pa, vv, acc[pnl], 0, 0, 0);
      }
    }
  }

  // ---- cross-wave reduce + divide by Z ----
  float* red = (float*)myst;   // 16 rows x 64 cols fp32 = 4 KB
#pragma unroll
  for (int pnl = 0; pnl < 4; ++pnl)
#pragma unroll
    for (int r = 0; r < 4; ++r)
      red[(4 * g + r) * DHEAD + pnl * 16 + qr] = acc[pnl][r];
  __syncthreads();
#pragma unroll
  for (int oo = 0; oo < 2; ++oo) {
    const int o = tid * 2 + oo;
    const int i = o >> 6, n = o & 63;
    float s = 0.f;
#pragma unroll
    for (int j = 0; j < WAVES; ++j) s += ((const float*)&stage[j][0])[i * DHEAD + n];
    attn_out[(qrow0 + i) * DHEAD + n] = s / zrow[i];
  }
}

// ---------------------------------------------------------------------------
// Kernel C: out = attn_out @ W_out + b_out (fp32). 32 rows x 256 cols per WG.
// ---------------------------------------------------------------------------
__global__ __launch_bounds__(256) void out_proj(
    const float* __restrict__ attn, const float* __restrict__ Wo,
    const float* __restrict__ bo, float* __restrict__ out)
{
  __shared__ float wl[32][DMODEL];  // 32 KB
  __shared__ float at[32][DHEAD];   // 8 KB
  const int t = threadIdx.x;
  const int row0 = blockIdx.x * 32;
  const int rg = t >> 6;
  const int cg = t & 63;
  float acc[8][4];
#pragma unroll
  for (int i = 0; i < 8; ++i) { acc[i][0] = acc[i][1] = acc[i][2] = acc[i][3] = 0.f; }
#pragma unroll
  for (int j = 0; j < 8; ++j) {
    int li = j * 256 + t;
    at[li >> 6][li & 63] = attn[(size_t)(row0 + (li >> 6)) * DHEAD + (li & 63)];
  }
  for (int kc = 0; kc < 2; ++kc) {
#pragma unroll
    for (int j = 0; j < 32; ++j) {
      int li = j * 256 + t;
      wl[li >> 8][li & 255] = Wo[(size_t)(kc * 32 + (li >> 8)) * DMODEL + (li & 255)];
    }
    __syncthreads();
#pragma unroll
    for (int kk = 0; kk < 32; ++kk) {
      const float4 wv = *(const float4*)&wl[kk][cg * 4];
#pragma unroll
      for (int i = 0; i < 8; ++i) {
        const float a = at[rg * 8 + i][kc * 32 + kk];
        acc[i][0] = fmaf(a, wv.x, acc[i][0]);
        acc[i][1] = fmaf(a, wv.y, acc[i][1]);
        acc[i][2] = fmaf(a, wv.z, acc[i][2]);
        acc[i][3] = fmaf(a, wv.w, acc[i][3]);
      }
    }
    __syncthreads();
  }
  const float4 bb = *(const float4*)&bo[cg * 4];
#pragma unroll
  for (int i = 0; i < 8; ++i) {
    float4 r;
    r.x = acc[i][0] + bb.x; r.y = acc[i][1] + bb.y;
    r.z = acc[i][2] + bb.z; r.w = acc[i][3] + bb.w;
    *(float4*)&out[(size_t)(row0 + rg * 8 + i) * DMODEL + cg * 4] = r;
  }
}

// ---------------------------------------------------------------------------
extern "C" void kernel_launch(void* const* d_in, const int* in_sizes, int n_in,
                              void* d_out, int out_size, void* d_ws, size_t ws_size,
                              hipStream_t stream)
{
  (void)in_sizes; (void)n_in; (void)out_size; (void)ws_size;
  const float* x  = (const float*)d_in[0];
  const float* Wq = (const float*)d_in[1];
  const float* bq = (const float*)d_in[2];
  const float* Wo = (const float*)d_in[3];
  const float* bo = (const float*)d_in[4];
  float* out = (float*)d_out;
  char* ws = (char*)d_ws;
  f16* qh = (f16*)(ws);                              // 2 MB
  f16* kh = (f16*)(ws + (size_t)(2 << 20));          // 2 MB
  f16* vt = (f16*)(ws + (size_t)(4 << 20));          // 2 MB (transposed V)
  float* attn = (float*)(ws + (size_t)(6 << 20));    // 4 MB

  hipLaunchKernelGGL(qkv_proj,   dim3(512),  dim3(256), 0, stream, x, Wq, bq, qh, kh, vt);
  hipLaunchKernelGGL(attn_fused, dim3(1024), dim3(512), 0, stream, qh, kh, vt, attn);
  hipLaunchKernelGGL(out_proj,   dim3(512),  dim3(256), 0, stream, attn, Wo, bo, out);
}

// Round 5
// 179.385 us; speedup vs baseline: 1.4588x; 1.0264x over previous
//
#include <hip/hip_runtime.h>
#include <hip/hip_fp16.h>
#include <stdint.h>

typedef _Float16 f16;
typedef _Float16 half8  __attribute__((ext_vector_type(8)));
typedef _Float16 half4v __attribute__((ext_vector_type(4)));
typedef float    f32x4  __attribute__((ext_vector_type(4)));

#define NBATCH 4
#define SEQ    4096
#define DMODEL 256
#define DHEAD  64
#define NQKV   192

// ---------------------------------------------------------------------------
// Kernel A: qkv = x @ W_qkv + b_qkv (fp32 VALU). Emits:
//   qh[row][d]   fp16, pre-scaled by 1/8 (exact pow2)
//   kh[row][d]   fp16 row-major        (QK^T stages this)
//   vt[b][d][seq] fp16 transposed      (PV stages this d-major)
// ---------------------------------------------------------------------------
__global__ __launch_bounds__(256) void qkv_proj(
    const float* __restrict__ x, const float* __restrict__ Wq,
    const float* __restrict__ bq,
    f16* __restrict__ qh, f16* __restrict__ kh, f16* __restrict__ vt)
{
  __shared__ float xs[32][64];      // 8 KB
  __shared__ float wsh[64][NQKV];   // 48 KB
  const int t = threadIdx.x;
  const int row0 = blockIdx.x * 32;
  const int cg = t & 31;            // 32 col-groups x 6 cols
  const int rg = t >> 5;            // 8 row-groups x 4 rows
  const int n0 = cg * 6;
  const int m0 = rg * 4;
  float acc[4][6];
#pragma unroll
  for (int i = 0; i < 4; ++i)
#pragma unroll
    for (int j = 0; j < 6; ++j) acc[i][j] = 0.f;

  for (int kc = 0; kc < 4; ++kc) {
    const int k0 = kc * 64;
#pragma unroll
    for (int j = 0; j < 8; ++j) {
      int li = j * 256 + t;
      xs[li >> 6][li & 63] = x[(size_t)(row0 + (li >> 6)) * DMODEL + k0 + (li & 63)];
    }
#pragma unroll
    for (int j = 0; j < 48; ++j) {
      int li = j * 256 + t;
      int r = li / NQKV, c = li % NQKV;
      wsh[r][c] = Wq[(size_t)(k0 + r) * NQKV + c];
    }
    __syncthreads();
#pragma unroll
    for (int kk4 = 0; kk4 < 16; ++kk4) {
      float4 a4[4];
#pragma unroll
      for (int i = 0; i < 4; ++i) a4[i] = *(const float4*)&xs[m0 + i][kk4 * 4];
#pragma unroll
      for (int e = 0; e < 4; ++e) {
        const int kk = kk4 * 4 + e;
        float2 b01 = *(const float2*)&wsh[kk][n0];
        float2 b23 = *(const float2*)&wsh[kk][n0 + 2];
        float2 b45 = *(const float2*)&wsh[kk][n0 + 4];
#pragma unroll
        for (int i = 0; i < 4; ++i) {
          const float a = (e == 0) ? a4[i].x : (e == 1) ? a4[i].y : (e == 2) ? a4[i].z : a4[i].w;
          acc[i][0] = fmaf(a, b01.x, acc[i][0]);
          acc[i][1] = fmaf(a, b01.y, acc[i][1]);
          acc[i][2] = fmaf(a, b23.x, acc[i][2]);
          acc[i][3] = fmaf(a, b23.y, acc[i][3]);
          acc[i][4] = fmaf(a, b45.x, acc[i][4]);
          acc[i][5] = fmaf(a, b45.y, acc[i][5]);
        }
      }
    }
    __syncthreads();
  }
  const int bi  = row0 >> 12;           // batch
  const int seq0 = (row0 & (SEQ - 1)) + m0;
#pragma unroll
  for (int j = 0; j < 6; ++j) {
    const int n = n0 + j;
    const float b = bq[n];
    const float v0 = acc[0][j] + b, v1 = acc[1][j] + b;
    const float v2 = acc[2][j] + b, v3 = acc[3][j] + b;
    if (n < 64) {
      const size_t r = (size_t)row0 + m0;
      qh[(r + 0) * DHEAD + n] = (f16)(v0 * 0.125f);
      qh[(r + 1) * DHEAD + n] = (f16)(v1 * 0.125f);
      qh[(r + 2) * DHEAD + n] = (f16)(v2 * 0.125f);
      qh[(r + 3) * DHEAD + n] = (f16)(v3 * 0.125f);
    } else if (n < 128) {
      const size_t r = (size_t)row0 + m0;
      kh[(r + 0) * DHEAD + (n - 64)] = (f16)v0;
      kh[(r + 1) * DHEAD + (n - 64)] = (f16)v1;
      kh[(r + 2) * DHEAD + (n - 64)] = (f16)v2;
      kh[(r + 3) * DHEAD + (n - 64)] = (f16)v3;
    } else {
      half4v pk = {(f16)v0, (f16)v1, (f16)v2, (f16)v3};
      *(half4v*)(vt + (size_t)bi * DHEAD * SEQ + (size_t)(n - 128) * SEQ + seq0) = pk;
    }
  }
}

// ---------------------------------------------------------------------------
// Kernel B: fused scores -> top-k threshold -> masked softmax -> PV.
// QK^T: K staged row-major, swizzled, PERMUTED key order: tile kt row r' is
// key 8*(r'>>2)+4kt+(r'&3), so each lane's P quads per 32-chunk are keys
// 8g..8g+7 -> PV B-frag (P^T) is a pure register concat. PV computes
// O^T = V^T P^T via mfma_16x16x32 with A = V^T staged d-major (contiguous
// b128 reads, XOR-swizzled 16B blocks).
// ---------------------------------------------------------------------------
#define WAVES  8
#define CHUNK  32
#define NCHUNK 16
#define WSTG   2176    // halves/wave region (4352 B): K 4KB | V 4KB | red 16x68 f32

__device__ __forceinline__ int khash(int row) {   // injective per permuted tile
  return ((row >> 2) & 6) | ((row >> 1) & 1);
}

__global__ __launch_bounds__(512) void attn_fused(
    const f16* __restrict__ qh, const f16* __restrict__ kh,
    const f16* __restrict__ vt, float* __restrict__ attn_out)
{
  __shared__ f16 stage[WAVES][WSTG];          // 34 KB, wave-private
  __shared__ float selbuf[2][WAVES][16];
  __shared__ float zrow[16];

  const int tid = threadIdx.x;
  const int w = tid >> 6;
  const int l = tid & 63;
  const int qr = l & 15;          // q-row (QK^T cols / PV cols)
  const int g  = l >> 4;          // lane group 0..3
  const int bi = blockIdx.x >> 8;
  const int rb = blockIdx.x & 255;
  const size_t qrow0  = (size_t)bi * SEQ + (size_t)rb * 16;
  const size_t kvbase = (size_t)bi * SEQ * DHEAD;
  const int key0 = w * (CHUNK * NCHUNK);

  f16* const myst = &stage[w][0];

  // Q fragments (B operand), q pre-scaled by 1/8 in qh.
  half8 qf0, qf1;
  {
    const f16* qp = qh + (qrow0 + qr) * DHEAD;
    qf0 = *(const half8*)(qp + 8 * g);
    qf1 = *(const half8*)(qp + 32 + 8 * g);
  }

  half4v P[2 * NCHUNK];   // P[2kc+kt][r] = S[qr][32kc + 8g + 4kt + r]
  float mn = 1e30f, mx = -1e30f;

  // ---- QK^T ----
#pragma unroll
  for (int kc = 0; kc < NCHUNK; ++kc) {
    const f16* src = kh + kvbase + (size_t)(key0 + kc * CHUNK) * DHEAD;
#pragma unroll
    for (int i = 0; i < 4; ++i) {
      const int keyl = i * 8 + (l >> 3);
      const int c8 = l & 7;
      uint4 d = *(const uint4*)(src + keyl * DHEAD + c8 * 8);
      *(uint4*)(myst + keyl * DHEAD + ((c8 ^ khash(keyl)) * 8)) = d;
    }
    // wave-private region: DS ops in-order per wave; no barrier needed.
#pragma unroll
    for (int kt = 0; kt < 2; ++kt) {
      const int rowk = 8 * (qr >> 2) + 4 * kt + (qr & 3);   // permuted key row
      const int h = khash(rowk);
      f32x4 c = {0.f, 0.f, 0.f, 0.f};
      half8 kf0 = *(const half8*)(myst + rowk * DHEAD + ((g ^ h) * 8));
      c = __builtin_amdgcn_mfma_f32_16x16x32_f16(kf0, qf0, c, 0, 0, 0);
      half8 kf1 = *(const half8*)(myst + rowk * DHEAD + (((4 + g) ^ h) * 8));
      c = __builtin_amdgcn_mfma_f32_16x16x32_f16(kf1, qf1, c, 0, 0, 0);
      mn = fminf(mn, fminf(fminf(c[0], c[1]), fminf(c[2], c[3])));
      mx = fmaxf(mx, fmaxf(fmaxf(c[0], c[1]), fmaxf(c[2], c[3])));
      P[kc * 2 + kt] = (half4v){(f16)c[0], (f16)c[1], (f16)c[2], (f16)c[3]};
    }
  }

  // ---- per-row min/max across lanes and waves ----
  mn = fminf(mn, __shfl_xor(mn, 16, 64));
  mn = fminf(mn, __shfl_xor(mn, 32, 64));
  mx = fmaxf(mx, __shfl_xor(mx, 16, 64));
  mx = fmaxf(mx, __shfl_xor(mx, 32, 64));
  __syncthreads();
  if (l < 16) { selbuf[0][w][l] = mn; selbuf[1][w][l] = mx; }
  __syncthreads();
  float lo = 1e30f, hi = -1e30f;
#pragma unroll
  for (int j = 0; j < WAVES; ++j) {
    lo = fminf(lo, selbuf[0][j][qr]);
    hi = fmaxf(hi, selbuf[1][j][qr]);
  }
  __syncthreads();   // lo/hi reads done before iter 0 overwrites selbuf[0]

  // ---- bisection on sampled count (1024 of 4096; target 512) ----
#pragma unroll
  for (int it = 0; it < 10; ++it) {
    const float tm = 0.5f * (lo + hi);
    const f16 th = (f16)tm;
    int cnt = 0;
#pragma unroll
    for (int j = 0; j < 2 * NCHUNK; j += 4) {
      half4v s = P[j];
      cnt += (s[0] >= th) + (s[1] >= th) + (s[2] >= th) + (s[3] >= th);
    }
    cnt += __shfl_xor(cnt, 16, 64);
    cnt += __shfl_xor(cnt, 32, 64);
    if (l < 16) selbuf[it & 1][w][l] = (float)cnt;
    __syncthreads();
    float tot = 0.f;
#pragma unroll
    for (int j = 0; j < WAVES; ++j) tot += selbuf[it & 1][j][qr];
    if (tot >= 512.f) lo = tm; else hi = tm;
  }
  const float thr = lo;

  // ---- exp in place (masked -> exp(0)=1, matches softmax(scores*mask)) ----
  float z = 0.f;
#pragma unroll
  for (int j = 0; j < 2 * NCHUNK; ++j) {
    half4v s = P[j];
    float p0 = (float)s[0], p1 = (float)s[1], p2 = (float)s[2], p3 = (float)s[3];
    p0 = (p0 >= thr) ? __expf(p0) : 1.f;
    p1 = (p1 >= thr) ? __expf(p1) : 1.f;
    p2 = (p2 >= thr) ? __expf(p2) : 1.f;
    p3 = (p3 >= thr) ? __expf(p3) : 1.f;
    z += (p0 + p1) + (p2 + p3);
    P[j] = (half4v){(f16)p0, (f16)p1, (f16)p2, (f16)p3};
  }
  z += __shfl_xor(z, 16, 64);
  z += __shfl_xor(z, 32, 64);
  if (l < 16) selbuf[0][w][l] = z;
  __syncthreads();
  if (w == 0 && l < 16) {
    float t2 = 0.f;
#pragma unroll
    for (int j = 0; j < WAVES; ++j) t2 += selbuf[0][j][l];
    zrow[l] = t2;   // consumed after the post-PV barrier
  }

  // ---- PV: O^T = V^T P^T. A = V^T (d-major LDS, b128 reads), B = P concat ----
  f32x4 acc[4];
#pragma unroll
  for (int p = 0; p < 4; ++p) acc[p] = (f32x4){0.f, 0.f, 0.f, 0.f};

  const f16* vsrc0 = vt + (size_t)bi * DHEAD * SEQ + key0;
#pragma unroll
  for (int kc = 0; kc < NCHUNK; ++kc) {
    const f16* src = vsrc0 + kc * CHUNK;
#pragma unroll
    for (int i = 0; i < 4; ++i) {
      const int d = i * 16 + (l >> 2);        // 16 d-rows per instr
      const int b = l & 3;                    // 8-key (16B) block
      uint4 dta = *(const uint4*)(src + (size_t)d * SEQ + b * 8);
      *(uint4*)(myst + d * CHUNK + ((b ^ (d & 3)) * 8)) = dta;
    }
    const half8 pb = __builtin_shufflevector(P[kc * 2], P[kc * 2 + 1],
                                             0, 1, 2, 3, 4, 5, 6, 7);
#pragma unroll
    for (int pnl = 0; pnl < 4; ++pnl) {
      const int d = 16 * pnl + qr;
      half8 va = *(const half8*)(myst + d * CHUNK + ((g ^ (d & 3)) * 8));
      acc[pnl] = __builtin_amdgcn_mfma_f32_16x16x32_f16(va, pb, acc[pnl], 0, 0, 0);
    }
  }

  // ---- cross-wave reduce + divide by Z ----
  // acc[pnl][r] = O[q=qr][d = 16pnl + 4g + r] -> float4 store, 68-pad rows
  float* red = (float*)myst;   // 16 rows x 68 floats = 4352 B
#pragma unroll
  for (int pnl = 0; pnl < 4; ++pnl)
    *(f32x4*)&red[qr * 68 + pnl * 16 + 4 * g] = acc[pnl];
  __syncthreads();
#pragma unroll
  for (int oo = 0; oo < 2; ++oo) {
    const int o = tid * 2 + oo;
    const int i = o >> 6, n = o & 63;
    float s = 0.f;
#pragma unroll
    for (int j = 0; j < WAVES; ++j) s += ((const float*)&stage[j][0])[i * 68 + n];
    attn_out[(qrow0 + i) * DHEAD + n] = s / zrow[i];
  }
}

// ---------------------------------------------------------------------------
// Kernel C: out = attn_out @ W_out + b_out (fp32). 32 rows x 256 cols per WG.
// ---------------------------------------------------------------------------
__global__ __launch_bounds__(256) void out_proj(
    const float* __restrict__ attn, const float* __restrict__ Wo,
    const float* __restrict__ bo, float* __restrict__ out)
{
  __shared__ float wl[32][DMODEL];  // 32 KB
  __shared__ float at[32][DHEAD];   // 8 KB
  const int t = threadIdx.x;
  const int row0 = blockIdx.x * 32;
  const int rg = t >> 6;
  const int cg = t & 63;
  float acc[8][4];
#pragma unroll
  for (int i = 0; i < 8; ++i) { acc[i][0] = acc[i][1] = acc[i][2] = acc[i][3] = 0.f; }
#pragma unroll
  for (int j = 0; j < 8; ++j) {
    int li = j * 256 + t;
    at[li >> 6][li & 63] = attn[(size_t)(row0 + (li >> 6)) * DHEAD + (li & 63)];
  }
  for (int kc = 0; kc < 2; ++kc) {
#pragma unroll
    for (int j = 0; j < 32; ++j) {
      int li = j * 256 + t;
      wl[li >> 8][li & 255] = Wo[(size_t)(kc * 32 + (li >> 8)) * DMODEL + (li & 255)];
    }
    __syncthreads();
#pragma unroll
    for (int kk = 0; kk < 32; ++kk) {
      const float4 wv = *(const float4*)&wl[kk][cg * 4];
#pragma unroll
      for (int i = 0; i < 8; ++i) {
        const float a = at[rg * 8 + i][kc * 32 + kk];
        acc[i][0] = fmaf(a, wv.x, acc[i][0]);
        acc[i][1] = fmaf(a, wv.y, acc[i][1]);
        acc[i][2] = fmaf(a, wv.z, acc[i][2]);
        acc[i][3] = fmaf(a, wv.w, acc[i][3]);
      }
    }
    __syncthreads();
  }
  const float4 bb = *(const float4*)&bo[cg * 4];
#pragma unroll
  for (int i = 0; i < 8; ++i) {
    float4 r;
    r.x = acc[i][0] + bb.x; r.y = acc[i][1] + bb.y;
    r.z = acc[i][2] + bb.z; r.w = acc[i][3] + bb.w;
    *(float4*)&out[(size_t)(row0 + rg * 8 + i) * DMODEL + cg * 4] = r;
  }
}

// ---------------------------------------------------------------------------
extern "C" void kernel_launch(void* const* d_in, const int* in_sizes, int n_in,
                              void* d_out, int out_size, void* d_ws, size_t ws_size,
                              hipStream_t stream)
{
  (void)in_sizes; (void)n_in; (void)out_size; (void)ws_size;
  const float* x  = (const float*)d_in[0];
  const float* Wq = (const float*)d_in[1];
  const float* bq = (const float*)d_in[2];
  const float* Wo = (const float*)d_in[3];
  const float* bo = (const float*)d_in[4];
  float* out = (float*)d_out;
  char* ws = (char*)d_ws;
  f16* qh = (f16*)(ws);                              // 2 MB
  f16* kh = (f16*)(ws + (size_t)(2 << 20));          // 2 MB
  f16* vt = (f16*)(ws + (size_t)(4 << 20));          // 2 MB (transposed V)
  float* attn = (float*)(ws + (size_t)(6 << 20));    // 4 MB

  hipLaunchKernelGGL(qkv_proj,   dim3(512),  dim3(256), 0, stream, x, Wq, bq, qh, kh, vt);
  hipLaunchKernelGGL(attn_fused, dim3(1024), dim3(512), 0, stream, qh, kh, vt, attn);
  hipLaunchKernelGGL(out_proj,   dim3(512),  dim3(256), 0, stream, attn, Wo, bo, out);
}

// Round 7
// 140.565 us; speedup vs baseline: 1.8617x; 1.2762x over previous
//
#include <hip/hip_runtime.h>
#include <hip/hip_fp16.h>
#include <stdint.h>

typedef _Float16 f16;
typedef _Float16 half8  __attribute__((ext_vector_type(8)));
typedef _Float16 half4v __attribute__((ext_vector_type(4)));
typedef float    f32x4  __attribute__((ext_vector_type(4)));

#define NBATCH 4
#define SEQ    4096
#define DMODEL 256
#define DHEAD  64
#define NQKV   192

// ---------------------------------------------------------------------------
// Kernel A: qkv = x @ W_qkv + b_qkv (fp32 VALU). Emits:
//   qh[row][d]   fp16, pre-scaled by 1/8 (exact pow2)
//   kh[row][d]   fp16 row-major        (QK^T stages this)
//   vt[b][d][seq] fp16 transposed      (PV stages this d-major)
// ---------------------------------------------------------------------------
__global__ __launch_bounds__(256) void qkv_proj(
    const float* __restrict__ x, const float* __restrict__ Wq,
    const float* __restrict__ bq,
    f16* __restrict__ qh, f16* __restrict__ kh, f16* __restrict__ vt)
{
  __shared__ float xs[32][64];      // 8 KB
  __shared__ float wsh[64][NQKV];   // 48 KB
  const int t = threadIdx.x;
  const int row0 = blockIdx.x * 32;
  const int cg = t & 31;            // 32 col-groups x 6 cols
  const int rg = t >> 5;            // 8 row-groups x 4 rows
  const int n0 = cg * 6;
  const int m0 = rg * 4;
  float acc[4][6];
#pragma unroll
  for (int i = 0; i < 4; ++i)
#pragma unroll
    for (int j = 0; j < 6; ++j) acc[i][j] = 0.f;

  for (int kc = 0; kc < 4; ++kc) {
    const int k0 = kc * 64;
#pragma unroll
    for (int j = 0; j < 8; ++j) {
      int li = j * 256 + t;
      xs[li >> 6][li & 63] = x[(size_t)(row0 + (li >> 6)) * DMODEL + k0 + (li & 63)];
    }
#pragma unroll
    for (int j = 0; j < 48; ++j) {
      int li = j * 256 + t;
      int r = li / NQKV, c = li % NQKV;
      wsh[r][c] = Wq[(size_t)(k0 + r) * NQKV + c];
    }
    __syncthreads();
#pragma unroll
    for (int kk4 = 0; kk4 < 16; ++kk4) {
      float4 a4[4];
#pragma unroll
      for (int i = 0; i < 4; ++i) a4[i] = *(const float4*)&xs[m0 + i][kk4 * 4];
#pragma unroll
      for (int e = 0; e < 4; ++e) {
        const int kk = kk4 * 4 + e;
        float2 b01 = *(const float2*)&wsh[kk][n0];
        float2 b23 = *(const float2*)&wsh[kk][n0 + 2];
        float2 b45 = *(const float2*)&wsh[kk][n0 + 4];
#pragma unroll
        for (int i = 0; i < 4; ++i) {
          const float a = (e == 0) ? a4[i].x : (e == 1) ? a4[i].y : (e == 2) ? a4[i].z : a4[i].w;
          acc[i][0] = fmaf(a, b01.x, acc[i][0]);
          acc[i][1] = fmaf(a, b01.y, acc[i][1]);
          acc[i][2] = fmaf(a, b23.x, acc[i][2]);
          acc[i][3] = fmaf(a, b23.y, acc[i][3]);
          acc[i][4] = fmaf(a, b45.x, acc[i][4]);
          acc[i][5] = fmaf(a, b45.y, acc[i][5]);
        }
      }
    }
    __syncthreads();
  }
  const int bi  = row0 >> 12;           // batch
  const int seq0 = (row0 & (SEQ - 1)) + m0;
#pragma unroll
  for (int j = 0; j < 6; ++j) {
    const int n = n0 + j;
    const float b = bq[n];
    const float v0 = acc[0][j] + b, v1 = acc[1][j] + b;
    const float v2 = acc[2][j] + b, v3 = acc[3][j] + b;
    if (n < 64) {
      const size_t r = (size_t)row0 + m0;
      qh[(r + 0) * DHEAD + n] = (f16)(v0 * 0.125f);
      qh[(r + 1) * DHEAD + n] = (f16)(v1 * 0.125f);
      qh[(r + 2) * DHEAD + n] = (f16)(v2 * 0.125f);
      qh[(r + 3) * DHEAD + n] = (f16)(v3 * 0.125f);
    } else if (n < 128) {
      const size_t r = (size_t)row0 + m0;
      kh[(r + 0) * DHEAD + (n - 64)] = (f16)v0;
      kh[(r + 1) * DHEAD + (n - 64)] = (f16)v1;
      kh[(r + 2) * DHEAD + (n - 64)] = (f16)v2;
      kh[(r + 3) * DHEAD + (n - 64)] = (f16)v3;
    } else {
      half4v pk = {(f16)v0, (f16)v1, (f16)v2, (f16)v3};
      *(half4v*)(vt + (size_t)bi * DHEAD * SEQ + (size_t)(n - 128) * SEQ + seq0) = pk;
    }
  }
}

// ---------------------------------------------------------------------------
// Kernel B: fused scores -> threshold -> masked softmax -> PV.
// Wave-private async staging via global_load_lds, double-buffered, counted
// vmcnt(4). RACE FIX vs R6: sched_barrier(0) between the MFMA cluster and the
// next stage issue. DS ops complete in-order per wave, so the lgkmcnt wait
// before the last MFMA guarantees ALL ds_reads of the buffer completed before
// the (pinned-below) DMA issue can overwrite it.
// ---------------------------------------------------------------------------
#define WAVES  8
#define CHUNK  32
#define NCHUNK 16
#define BUFH   2048    // halves per buffer (4 KB = 32 rows x 64 halves)

__device__ __forceinline__ int khash(int row) {   // bijective per permuted tile
  return ((row >> 2) & 6) | ((row >> 1) & 1);
}

typedef __attribute__((address_space(3))) f16 as3_f16;
typedef __attribute__((address_space(1))) const f16 as1_f16;

__device__ __forceinline__ void gll16(const f16* g, f16* l) {
  __builtin_amdgcn_global_load_lds((as1_f16*)g, (as3_f16*)l, 16, 0, 0);
}

#define SCHED_PIN __builtin_amdgcn_sched_barrier(0)
#define WAITVM4 do { asm volatile("s_waitcnt vmcnt(4)" ::: "memory"); \
                     __builtin_amdgcn_sched_barrier(0); } while (0)
#define WAITVM0 do { asm volatile("s_waitcnt vmcnt(0)" ::: "memory"); \
                     __builtin_amdgcn_sched_barrier(0); } while (0)

// K chunk -> LDS[row 0..31][slot 0..7], source slot pre-XOR'd with khash(row)
__device__ __forceinline__ void stage_k(const f16* kchunk, f16* buf, int l) {
#pragma unroll
  for (int i = 0; i < 4; ++i) {
    const int row = i * 8 + (l >> 3);
    const int c8 = (l & 7) ^ khash(row);
    gll16(kchunk + row * DHEAD + c8 * 8, buf + i * 512);
  }
}

// V chunk -> LDS rows = d&31 (128 B), slots 0..3 = d<32, 4..7 = d>=32, XOR r&7
__device__ __forceinline__ void stage_v(const f16* vchunk, f16* buf, int l) {
#pragma unroll
  for (int i = 0; i < 4; ++i) {
    const int r = i * 8 + (l >> 3);
    const int jj = (l & 7) ^ (r & 7);
    const int d = ((jj >> 2) << 5) + r;
    const int kb = jj & 3;
    gll16(vchunk + (size_t)d * SEQ + kb * 8, buf + i * 512);
  }
}

__global__ __launch_bounds__(512) void attn_fused(
    const f16* __restrict__ qh, const f16* __restrict__ kh,
    const f16* __restrict__ vt, float* __restrict__ attn_out)
{
  __shared__ f16 stage[WAVES][2 * BUFH];     // 64 KB: per-wave double buffer
  __shared__ float selbuf[2][WAVES][16];
  __shared__ float zrow[16];

  const int tid = threadIdx.x;
  const int w = tid >> 6;
  const int l = tid & 63;
  const int qr = l & 15;
  const int g  = l >> 4;
  const int bi = blockIdx.x >> 8;
  const int rb = blockIdx.x & 255;
  const size_t qrow0  = (size_t)bi * SEQ + (size_t)rb * 16;
  const size_t kvbase = (size_t)bi * SEQ * DHEAD;
  const int key0 = w * (CHUNK * NCHUNK);

  f16* const mybuf = &stage[w][0];

  // Q fragments (B operand), q pre-scaled by 1/8 in qh.
  half8 qf0, qf1;
  {
    const f16* qp = qh + (qrow0 + qr) * DHEAD;
    qf0 = *(const half8*)(qp + 8 * g);
    qf1 = *(const half8*)(qp + 32 + 8 * g);
  }

  half4v P[2 * NCHUNK];   // P[2kc+kt][r] = S[qr][32kc + 8g + 4kt + r]
  float mn = 1e30f, mx = -1e30f;

  // ---- QK^T: async pipeline, no barriers ----
  const f16* kc0 = kh + kvbase + (size_t)key0 * DHEAD;
  stage_k(kc0, mybuf, l);
  stage_k(kc0 + 32 * DHEAD, mybuf + BUFH, l);
#pragma unroll
  for (int kc = 0; kc < NCHUNK; ++kc) {
    if (kc < NCHUNK - 1) { WAITVM4; } else { WAITVM0; }
    const f16* bufp = mybuf + (kc & 1) * BUFH;
#pragma unroll
    for (int kt = 0; kt < 2; ++kt) {
      const int rowk = 8 * (qr >> 2) + 4 * kt + (qr & 3);   // permuted key row
      const int h = khash(rowk);
      f32x4 c = {0.f, 0.f, 0.f, 0.f};
      half8 kf0 = *(const half8*)(bufp + rowk * DHEAD + ((g ^ h) * 8));
      c = __builtin_amdgcn_mfma_f32_16x16x32_f16(kf0, qf0, c, 0, 0, 0);
      half8 kf1 = *(const half8*)(bufp + rowk * DHEAD + (((4 + g) ^ h) * 8));
      c = __builtin_amdgcn_mfma_f32_16x16x32_f16(kf1, qf1, c, 0, 0, 0);
      mn = fminf(mn, fminf(fminf(c[0], c[1]), fminf(c[2], c[3])));
      mx = fmaxf(mx, fmaxf(fmaxf(c[0], c[1]), fmaxf(c[2], c[3])));
      P[kc * 2 + kt] = (half4v){(f16)c[0], (f16)c[1], (f16)c[2], (f16)c[3]};
    }
    if (kc + 2 < NCHUNK) {
      SCHED_PIN;   // all reads of buf[kc&1] complete (in-order DS) before DMA
      stage_k(kc0 + (size_t)(kc + 2) * 32 * DHEAD, mybuf + (kc & 1) * BUFH, l);
    }
  }

  // ---- per-row min/max across lanes and waves ----
  mn = fminf(mn, __shfl_xor(mn, 16, 64));
  mn = fminf(mn, __shfl_xor(mn, 32, 64));
  mx = fmaxf(mx, __shfl_xor(mx, 16, 64));
  mx = fmaxf(mx, __shfl_xor(mx, 32, 64));
  if (l < 16) { selbuf[0][w][l] = mn; selbuf[1][w][l] = mx; }
  __syncthreads();
  float lo = 1e30f, hi = -1e30f;
#pragma unroll
  for (int j = 0; j < WAVES; ++j) {
    lo = fminf(lo, selbuf[0][j][qr]);
    hi = fmaxf(hi, selbuf[1][j][qr]);
  }
  __syncthreads();   // lo/hi reads done before iter 0 overwrites selbuf[0]

  // ---- bisection on sampled count (1024 of 4096; target 512) ----
#pragma unroll
  for (int it = 0; it < 10; ++it) {
    const float tm = 0.5f * (lo + hi);
    const f16 th = (f16)tm;
    int cnt = 0;
#pragma unroll
    for (int j = 0; j < 2 * NCHUNK; j += 4) {
      half4v s = P[j];
      cnt += (s[0] >= th) + (s[1] >= th) + (s[2] >= th) + (s[3] >= th);
    }
    cnt += __shfl_xor(cnt, 16, 64);
    cnt += __shfl_xor(cnt, 32, 64);
    if (l < 16) selbuf[it & 1][w][l] = (float)cnt;
    __syncthreads();
    float tot = 0.f;
#pragma unroll
    for (int j = 0; j < WAVES; ++j) tot += selbuf[it & 1][j][qr];
    if (tot >= 512.f) lo = tm; else hi = tm;
  }
  const float thr = lo;

  // ---- prefetch V chunks 0/1 (exp loop + z-barrier hide the latency) ----
  const f16* vchunk0 = vt + (size_t)bi * DHEAD * SEQ + key0;
  stage_v(vchunk0, mybuf, l);
  stage_v(vchunk0 + 32, mybuf + BUFH, l);

  // ---- exp in place (masked -> exp(0)=1, matches softmax(scores*mask)) ----
  float z = 0.f;
#pragma unroll
  for (int j = 0; j < 2 * NCHUNK; ++j) {
    half4v s = P[j];
    float p0 = (float)s[0], p1 = (float)s[1], p2 = (float)s[2], p3 = (float)s[3];
    p0 = (p0 >= thr) ? __expf(p0) : 1.f;
    p1 = (p1 >= thr) ? __expf(p1) : 1.f;
    p2 = (p2 >= thr) ? __expf(p2) : 1.f;
    p3 = (p3 >= thr) ? __expf(p3) : 1.f;
    z += (p0 + p1) + (p2 + p3);
    P[j] = (half4v){(f16)p0, (f16)p1, (f16)p2, (f16)p3};
  }
  z += __shfl_xor(z, 16, 64);
  z += __shfl_xor(z, 32, 64);
  if (l < 16) selbuf[0][w][l] = z;
  __syncthreads();
  if (w == 0 && l < 16) {
    float t2 = 0.f;
#pragma unroll
    for (int j = 0; j < WAVES; ++j) t2 += selbuf[0][j][l];
    zrow[l] = t2;   // consumed after the post-PV barrier
  }

  // ---- PV: O^T = V^T P^T; A = V^T (b128 LDS reads), B = P register concat ----
  f32x4 acc[4];
#pragma unroll
  for (int p = 0; p < 4; ++p) acc[p] = (f32x4){0.f, 0.f, 0.f, 0.f};

#pragma unroll
  for (int kc = 0; kc < NCHUNK; ++kc) {
    if (kc < NCHUNK - 1) { WAITVM4; } else { WAITVM0; }
    const f16* bufp = mybuf + (kc & 1) * BUFH;
    const half8 pb = __builtin_shufflevector(P[kc * 2], P[kc * 2 + 1],
                                             0, 1, 2, 3, 4, 5, 6, 7);
#pragma unroll
    for (int pnl = 0; pnl < 4; ++pnl) {
      const int d = 16 * pnl + qr;
      const int r = d & 31;
      const int j = (((d >> 5) << 2) + g) ^ (r & 7);
      half8 va = *(const half8*)(bufp + r * 64 + j * 8);
      acc[pnl] = __builtin_amdgcn_mfma_f32_16x16x32_f16(va, pb, acc[pnl], 0, 0, 0);
    }
    if (kc + 2 < NCHUNK) {
      SCHED_PIN;   // all reads of buf[kc&1] complete (in-order DS) before DMA
      stage_v(vchunk0 + (kc + 2) * 32, mybuf + (kc & 1) * BUFH, l);
    }
  }

  // ---- cross-wave reduce + divide by Z ----
  // acc[pnl][r] = O[q=qr][d = 16pnl + 4g + r] -> float4 store, 68-pad rows
  float* red = (float*)mybuf;   // 16 rows x 68 floats = 4352 B (fits in 8 KB)
#pragma unroll
  for (int pnl = 0; pnl < 4; ++pnl)
    *(f32x4*)&red[qr * 68 + pnl * 16 + 4 * g] = acc[pnl];
  __syncthreads();
#pragma unroll
  for (int oo = 0; oo < 2; ++oo) {
    const int o = tid * 2 + oo;
    const int i = o >> 6, n = o & 63;
    float s = 0.f;
#pragma unroll
    for (int j = 0; j < WAVES; ++j) s += ((const float*)&stage[j][0])[i * 68 + n];
    attn_out[(qrow0 + i) * DHEAD + n] = s / zrow[i];
  }
}

// ---------------------------------------------------------------------------
// Kernel C: out = attn_out @ W_out + b_out (fp32). 32 rows x 256 cols per WG.
// ---------------------------------------------------------------------------
__global__ __launch_bounds__(256) void out_proj(
    const float* __restrict__ attn, const float* __restrict__ Wo,
    const float* __restrict__ bo, float* __restrict__ out)
{
  __shared__ float wl[32][DMODEL];  // 32 KB
  __shared__ float at[32][DHEAD];   // 8 KB
  const int t = threadIdx.x;
  const int row0 = blockIdx.x * 32;
  const int rg = t >> 6;
  const int cg = t & 63;
  float acc[8][4];
#pragma unroll
  for (int i = 0; i < 8; ++i) { acc[i][0] = acc[i][1] = acc[i][2] = acc[i][3] = 0.f; }
#pragma unroll
  for (int j = 0; j < 8; ++j) {
    int li = j * 256 + t;
    at[li >> 6][li & 63] = attn[(size_t)(row0 + (li >> 6)) * DHEAD + (li & 63)];
  }
  for (int kc = 0; kc < 2; ++kc) {
#pragma unroll
    for (int j = 0; j < 32; ++j) {
      int li = j * 256 + t;
      wl[li >> 8][li & 255] = Wo[(size_t)(kc * 32 + (li >> 8)) * DMODEL + (li & 255)];
    }
    __syncthreads();
#pragma unroll
    for (int kk = 0; kk < 32; ++kk) {
      const float4 wv = *(const float4*)&wl[kk][cg * 4];
#pragma unroll
      for (int i = 0; i < 8; ++i) {
        const float a = at[rg * 8 + i][kc * 32 + kk];
        acc[i][0] = fmaf(a, wv.x, acc[i][0]);
        acc[i][1] = fmaf(a, wv.y, acc[i][1]);
        acc[i][2] = fmaf(a, wv.z, acc[i][2]);
        acc[i][3] = fmaf(a, wv.w, acc[i][3]);
      }
    }
    __syncthreads();
  }
  const float4 bb = *(const float4*)&bo[cg * 4];
#pragma unroll
  for (int i = 0; i < 8; ++i) {
    float4 r;
    r.x = acc[i][0] + bb.x; r.y = acc[i][1] + bb.y;
    r.z = acc[i][2] + bb.z; r.w = acc[i][3] + bb.w;
    *(float4*)&out[(size_t)(row0 + rg * 8 + i) * DMODEL + cg * 4] = r;
  }
}

// ---------------------------------------------------------------------------
extern "C" void kernel_launch(void* const* d_in, const int* in_sizes, int n_in,
                              void* d_out, int out_size, void* d_ws, size_t ws_size,
                              hipStream_t stream)
{
  (void)in_sizes; (void)n_in; (void)out_size; (void)ws_size;
  const float* x  = (const float*)d_in[0];
  const float* Wq = (const float*)d_in[1];
  const float* bq = (const float*)d_in[2];
  const float* Wo = (const float*)d_in[3];
  const float* bo = (const float*)d_in[4];
  float* out = (float*)d_out;
  char* ws = (char*)d_ws;
  f16* qh = (f16*)(ws);                              // 2 MB
  f16* kh = (f16*)(ws + (size_t)(2 << 20));          // 2 MB
  f16* vt = (f16*)(ws + (size_t)(4 << 20));          // 2 MB (transposed V)
  float* attn = (float*)(ws + (size_t)(6 << 20));    // 4 MB

  hipLaunchKernelGGL(qkv_proj,   dim3(512),  dim3(256), 0, stream, x, Wq, bq, qh, kh, vt);
  hipLaunchKernelGGL(attn_fused, dim3(1024), dim3(512), 0, stream, qh, kh, vt, attn);
  hipLaunchKernelGGL(out_proj,   dim3(512),  dim3(256), 0, stream, attn, Wo, bo, out);
}